// Round 12
// baseline (271.193 us; speedup 1.0000x reference)
//
#include <hip/hip_runtime.h>
#include <stdint.h>

#define Ttok 1024
#define Hdim 2048
#define Idim 1024
#define Enum 16
#define NKH  64
#define NKO  32

typedef __attribute__((ext_vector_type(8))) short  short8;
typedef __attribute__((ext_vector_type(4))) float  f32x4;

__device__ __forceinline__ unsigned short f2bf(float f) {
    union { float f; uint32_t u; } v; v.f = f;
    uint32_t u = v.u;
    return (unsigned short)((u + 0x7FFFu + ((u >> 16) & 1u)) >> 16);
}
__device__ __forceinline__ uint32_t cvtpk(float lo, float hi) {
    uint32_t d;
    asm("v_cvt_pk_bf16_f32 %0, %1, %2" : "=v"(d) : "v"(lo), "v"(hi));
    return d;
}
__device__ __forceinline__ void gld_lds16(const void* g, void* l) {
    __builtin_amdgcn_global_load_lds(
        (const __attribute__((address_space(1))) unsigned int*)g,
        (__attribute__((address_space(3))) unsigned int*)l, 16, 0, 0);
}

// ---------------- Router ----------------
__global__ __launch_bounds__(256) void k_router(
    const float* __restrict__ x, const float* __restrict__ gw,
    const float* __restrict__ bias,
    int* __restrict__ counts, int* __restrict__ tids, float* __restrict__ tws)
{
    __shared__ __align__(16) float xrow[Hdim];
    __shared__ float lg[Enum];
    const int t = blockIdx.x;
    const float* xr = x + (size_t)t * Hdim;

    for (int i = threadIdx.x; i < Hdim / 4; i += 256)
        ((f32x4*)xrow)[i] = ((const f32x4*)xr)[i];
    __syncthreads();

    const int lane = threadIdx.x & 63;
    const int wid  = threadIdx.x >> 6;
    for (int e = wid; e < Enum; e += 4) {
        const float* g = gw + (size_t)e * Hdim;
        float s = 0.f;
        for (int j = lane; j < Hdim; j += 64) s += xrow[j] * g[j];
        #pragma unroll
        for (int off = 32; off; off >>= 1) s += __shfl_xor(s, off);
        if (lane == 0) lg[e] = s;
    }
    __syncthreads();

    if (threadIdx.x == 0) {
        float m = lg[0];
        #pragma unroll
        for (int e = 1; e < Enum; ++e) m = fmaxf(m, lg[e]);
        float sc[Enum]; float sum = 0.f;
        #pragma unroll
        for (int e = 0; e < Enum; ++e) { float ex = expf(lg[e] - m); sc[e] = ex; sum += ex; }
        float inv = 1.f / sum;
        #pragma unroll
        for (int e = 0; e < Enum; ++e) sc[e] *= inv;
        int i0 = 0; float b0 = sc[0] + bias[0];
        #pragma unroll
        for (int e = 1; e < Enum; ++e) { float bb = sc[e] + bias[e]; if (bb > b0) { b0 = bb; i0 = e; } }
        int i1 = -1; float b1 = -1e30f;
        #pragma unroll
        for (int e = 0; e < Enum; ++e) {
            if (e == i0) continue;
            float bb = sc[e] + bias[e]; if (bb > b1) { b1 = bb; i1 = e; }
        }
        float w0 = sc[i0], w1v = sc[i1];
        float winv = 1.f / (w0 + w1v);
        w0 *= winv; w1v *= winv;
        int p0 = atomicAdd(&counts[i0], 1);
        tids[i0 * Ttok + p0] = t; tws[i0 * Ttok + p0] = w0;
        int p1 = atomicAdd(&counts[i1], 1);
        tids[i1 * Ttok + p1] = t; tws[i1 * Ttok + p1] = w1v;
    }
}

// ---------------- Gather: compact + bf16 + tile X (fixed 256 rows/expert) ----------------
__global__ __launch_bounds__(256) void k_gather(
    const float* __restrict__ x, const int* __restrict__ counts,
    const int* __restrict__ tids, unsigned short* __restrict__ Xg)
{
    const int e = blockIdx.y >> 2, c = blockIdx.y & 3;
    const int Ne = counts[e];
    const int s  = blockIdx.x;
    const int r  = threadIdx.x & 63;
    const int kq = threadIdx.x >> 6;
    const int row = c * 64 + r;
    const bool valid = row < Ne;
    const int tok = valid ? tids[e * Ttok + row] : 0;
    const float* xr = x + (size_t)tok * Hdim;

    #pragma unroll
    for (int j = 0; j < 8; ++j) {
        int kg = s * 32 + j * 4 + kq;
        uint4 o = make_uint4(0, 0, 0, 0);
        if (valid) {
            f32x4 p0 = *(const f32x4*)(xr + kg * 8);
            f32x4 p1 = *(const f32x4*)(xr + kg * 8 + 4);
            o.x = cvtpk(p0[0], p0[1]); o.y = cvtpk(p0[2], p0[3]);
            o.z = cvtpk(p1[0], p1[1]); o.w = cvtpk(p1[2], p1[3]);
        }
        *(uint4*)(Xg + ((size_t)(e * 256 + kg) * 256 + row) * 8) = o;
    }
}

// ---------------- Stage 2: He = silu(X@W1)*(X@W3), uniform flight-3 pipeline ----------------
// grid (16 cb, 16 e), block 512 (8 waves: wr=wid>>2 rows128, wc=wid&3 cols16).
__global__ __launch_bounds__(512, 1) void k_h(
    const unsigned short* __restrict__ Xg,
    const float* __restrict__ w1, const float* __restrict__ w3,
    unsigned short* __restrict__ He)
{
    const int e    = blockIdx.y;
    const int cb   = blockIdx.x;
    const int col0 = cb * 64;
    const int tid  = threadIdx.x;
    const int lane = tid & 63;
    const int wid  = tid >> 6;
    const int l15  = lane & 15;
    const int kq   = lane >> 4;
    const int wr   = wid >> 2, wc = wid & 3;

    __shared__ float          Wr[4][32][128];   // 64 KB fp32 [buf][krow][w1 0-63|w3 64-127], +16 rot on odd kq
    __shared__ unsigned short Ar[4][4][256][8]; // 64 KB bf16 [buf][kg][row][8]

    // A pieces (2/wave)
    const unsigned short* asrc[2]; int aoff[2];
    #pragma unroll
    for (int qq = 0; qq < 2; ++qq) {
        int q = wid * 2 + qq;
        asrc[qq] = Xg + ((size_t)(e * 256 + (q >> 2)) * 256 + (q & 3) * 64 + lane) * 8;
        aoff[qq] = q * 1024;
    }
    // W pieces (2/wave), source pre-rotated: stored col P holds global col (P - shift) & 127
    const float* wsrcp[2]; int woff[2];
    #pragma unroll
    for (int pp = 0; pp < 2; ++pp) {
        int p     = wid * 2 + pp;
        int kr    = p * 2 + (lane >> 5);
        int shift = ((p >> 2) & 1) * 16;
        int cg    = (((lane & 31) * 4) + 128 - shift) & 127;
        wsrcp[pp] = (cg < 64)
            ? (w1 + ((size_t)e * Hdim + kr) * Idim + col0 + cg)
            : (w3 + ((size_t)e * Hdim + kr) * Idim + col0 + (cg - 64));
        woff[pp] = p * 1024;
    }

    f32x4 acc1[8], acc3[8];
    #pragma unroll
    for (int a = 0; a < 8; ++a) { acc1[a] = (f32x4)(0.f); acc3[a] = (f32x4)(0.f); }

    char* ArB = (char*)&Ar[0][0][0][0];
    char* WrB = (char*)&Wr[0][0][0];

    auto ISSUE = [&](int s, int buf) {
        #pragma unroll
        for (int qq = 0; qq < 2; ++qq)
            gld_lds16(asrc[qq] + (size_t)s * 8192, ArB + buf * 16384 + aoff[qq]);
        #pragma unroll
        for (int pp = 0; pp < 2; ++pp)
            gld_lds16(wsrcp[pp] + (size_t)s * 32 * Idim, WrB + buf * 16384 + woff[pp]);
    };
    auto CONSUME = [&](int ri) {
        const int sh = (kq & 1) * 16;
        float b1f[8], b3f[8];
        #pragma unroll
        for (int j = 0; j < 8; ++j) {
            b1f[j] = Wr[ri][kq * 8 + j][(wc * 16 + l15 + sh) & 127];
            b3f[j] = Wr[ri][kq * 8 + j][(64 + wc * 16 + l15 + sh) & 127];
        }
        short8 b1, b3;
        uint32_t* b1u = (uint32_t*)&b1; uint32_t* b3u = (uint32_t*)&b3;
        #pragma unroll
        for (int j = 0; j < 4; ++j) {
            b1u[j] = cvtpk(b1f[2 * j], b1f[2 * j + 1]);
            b3u[j] = cvtpk(b3f[2 * j], b3f[2 * j + 1]);
        }
        #pragma unroll
        for (int fr = 0; fr < 8; ++fr) {
            short8 a = *(const short8*)&Ar[ri][kq][wr * 128 + fr * 16 + l15][0];
            acc1[fr] = __builtin_amdgcn_mfma_f32_16x16x32_bf16(a, b1, acc1[fr], 0, 0, 0);
            acc3[fr] = __builtin_amdgcn_mfma_f32_16x16x32_bf16(a, b3, acc3[fr], 0, 0, 0);
        }
    };

    ISSUE(0, 0); ISSUE(1, 1); ISSUE(2, 2);
    for (int s = 0; s < NKH; ++s) {
        asm volatile("s_waitcnt vmcnt(8)" ::: "memory");
        __builtin_amdgcn_s_barrier();
        int sn = s + 3 < NKH ? s + 3 : NKH - 1;
        ISSUE(sn, (s + 3) & 3);
        CONSUME(s & 3);
    }
    asm volatile("s_waitcnt vmcnt(0)" ::: "memory");

    // epilogue: he = silu(h1)*h3 -> He tiled [e][kg][row][8]
    const int colh = col0 + wc * 16 + l15;
    unsigned short* Hc = He + ((size_t)(e * 128 + (colh >> 3)) * 256) * 8 + (colh & 7);
    #pragma unroll
    for (int fr = 0; fr < 8; ++fr) {
        int rbase = wr * 128 + fr * 16 + kq * 4;
        #pragma unroll
        for (int k = 0; k < 4; ++k) {
            float h1 = acc1[fr][k], h3 = acc3[fr][k];
            float he = h1 * h3 * __builtin_amdgcn_rcpf(1.f + __expf(-h1));
            Hc[(size_t)(rbase + k) * 8] = f2bf(he);
        }
    }
}

// ---------------- Stage 3: out += w * (He @ W2), uniform flight-3 pipeline ----------------
// grid (16 cb, 16 e), block 512. M=256, N=128, BK=32, NK=32.
__global__ __launch_bounds__(512, 1) void k_o(
    const unsigned short* __restrict__ He,
    const float* __restrict__ w2,
    const int* __restrict__ counts, const int* __restrict__ tids,
    const float* __restrict__ tws,
    float* __restrict__ out)
{
    const int e    = blockIdx.y;
    const int Ne   = counts[e];
    const int col0 = blockIdx.x * 128;
    const int tid  = threadIdx.x;
    const int lane = tid & 63;
    const int wid  = tid >> 6;
    const int l15  = lane & 15;
    const int kq   = lane >> 4;
    const int wr   = wid >> 2, wc = wid & 3;

    __shared__ float          Wr[4][32][128];   // 64 KB fp32, rotated
    __shared__ unsigned short Ar[4][4][256][8]; // 64 KB bf16

    const unsigned short* asrc[2]; int aoff[2];
    #pragma unroll
    for (int qq = 0; qq < 2; ++qq) {
        int q = wid * 2 + qq;
        asrc[qq] = He + ((size_t)(e * 128 + (q >> 2)) * 256 + (q & 3) * 64 + lane) * 8;
        aoff[qq] = q * 1024;
    }
    const float* wsrcp[2]; int woff[2];
    #pragma unroll
    for (int pp = 0; pp < 2; ++pp) {
        int p     = wid * 2 + pp;
        int kr    = p * 2 + (lane >> 5);
        int shift = ((p >> 2) & 1) * 16;
        int cg    = (((lane & 31) * 4) + 128 - shift) & 127;
        wsrcp[pp] = w2 + ((size_t)e * Idim + kr) * Hdim + col0 + cg;
        woff[pp]  = p * 1024;
    }

    f32x4 acc[8][2];
    #pragma unroll
    for (int a = 0; a < 8; ++a) { acc[a][0] = (f32x4)(0.f); acc[a][1] = (f32x4)(0.f); }

    char* ArB = (char*)&Ar[0][0][0][0];
    char* WrB = (char*)&Wr[0][0][0];

    auto ISSUE = [&](int s, int buf) {
        #pragma unroll
        for (int qq = 0; qq < 2; ++qq)
            gld_lds16(asrc[qq] + (size_t)s * 8192, ArB + buf * 16384 + aoff[qq]);
        #pragma unroll
        for (int pp = 0; pp < 2; ++pp)
            gld_lds16(wsrcp[pp] + (size_t)s * 32 * Hdim, WrB + buf * 16384 + woff[pp]);
    };
    auto CONSUME = [&](int ri) {
        const int sh = (kq & 1) * 16;
        float bf[2][8];
        #pragma unroll
        for (int fc = 0; fc < 2; ++fc)
            #pragma unroll
            for (int j = 0; j < 8; ++j)
                bf[fc][j] = Wr[ri][kq * 8 + j][(wc * 32 + fc * 16 + l15 + sh) & 127];
        short8 b[2];
        #pragma unroll
        for (int fc = 0; fc < 2; ++fc) {
            uint32_t* bu = (uint32_t*)&b[fc];
            #pragma unroll
            for (int j = 0; j < 4; ++j)
                bu[j] = cvtpk(bf[fc][2 * j], bf[fc][2 * j + 1]);
        }
        #pragma unroll
        for (int fr = 0; fr < 8; ++fr) {
            short8 a = *(const short8*)&Ar[ri][kq][wr * 128 + fr * 16 + l15][0];
            acc[fr][0] = __builtin_amdgcn_mfma_f32_16x16x32_bf16(a, b[0], acc[fr][0], 0, 0, 0);
            acc[fr][1] = __builtin_amdgcn_mfma_f32_16x16x32_bf16(a, b[1], acc[fr][1], 0, 0, 0);
        }
    };

    ISSUE(0, 0); ISSUE(1, 1); ISSUE(2, 2);
    for (int s = 0; s < NKO; ++s) {
        asm volatile("s_waitcnt vmcnt(8)" ::: "memory");
        __builtin_amdgcn_s_barrier();
        int sn = s + 3 < NKO ? s + 3 : NKO - 1;
        ISSUE(sn, (s + 3) & 3);
        CONSUME(s & 3);
    }
    asm volatile("s_waitcnt vmcnt(0)" ::: "memory");

    #pragma unroll
    for (int fr = 0; fr < 8; ++fr) {
        #pragma unroll
        for (int k = 0; k < 4; ++k) {
            int grow = wr * 128 + fr * 16 + kq * 4 + k;
            if (grow < Ne) {
                int   tk = tids[e * Ttok + grow];
                float w  = tws[e * Ttok + grow];
                #pragma unroll
                for (int fc = 0; fc < 2; ++fc)
                    atomicAdd(&out[(size_t)tk * Hdim + col0 + wc * 32 + fc * 16 + l15],
                              w * acc[fr][fc][k]);
            }
        }
    }
}

extern "C" void kernel_launch(void* const* d_in, const int* in_sizes, int n_in,
                              void* d_out, int out_size, void* d_ws, size_t ws_size,
                              hipStream_t stream)
{
    const float* x    = (const float*)d_in[0];
    const float* gw   = (const float*)d_in[1];
    const float* bias = (const float*)d_in[2];
    const float* w1   = (const float*)d_in[3];
    const float* w3   = (const float*)d_in[4];
    const float* w2   = (const float*)d_in[5];
    float* out = (float*)d_out;

    char* ws = (char*)d_ws;
    int*            counts = (int*)ws;                         // @0        64 B
    int*            tids   = (int*)(ws + 1024);                // 64 KB
    float*          tws    = (float*)(ws + 66560);             // 64 KB
    unsigned short* Xg     = (unsigned short*)(ws + 132096);   // 16.78 MB [e][256kg][256r][8]
    unsigned short* He     = (unsigned short*)(ws + 16909312); // 8.39 MB  [e][128kg][256r][8]

    hipMemsetAsync(counts, 0, Enum * sizeof(int), stream);
    hipMemsetAsync(out, 0, (size_t)Ttok * Hdim * sizeof(float), stream);

    k_router<<<dim3(Ttok), dim3(256), 0, stream>>>(x, gw, bias, counts, tids, tws);
    k_gather<<<dim3(8, 64), dim3(256), 0, stream>>>(x, counts, tids, Xg);
    k_h<<<dim3(16, Enum), dim3(512), 0, stream>>>(Xg, w1, w3, He);
    k_o<<<dim3(16, Enum), dim3(512), 0, stream>>>(He, w2, counts, tids, tws, out);
}